// Round 1
// baseline (101.459 us; speedup 1.0000x reference)
//
#include <hip/hip_runtime.h>

// 25 qubits, DIM=2, targets (10, 3) on a row-major (2,)*25 array.
// Axis t has element stride 2^(24-t):
//   axis 10 -> stride 2^14 (gate index 'a')
//   axis 3  -> stride 2^21 (gate index 'b')
// Gate op[a, b, a', b'] flat index = a*8 + b*4 + a'*2 + b'.
// out[base + a*2^14 + b*2^21] = sum_{a',b'} M[a,b,a',b'] * in[base + a'*2^14 + b'*2^21]
// Complex split: outR = Mr*xr - Mi*xi ; outI = Mr*xi + Mi*xr.

#define N_STATE  (1u << 25)
#define S_A      (1u << 14)   // stride of target axis 10
#define S_B      (1u << 21)   // stride of target axis 3

// Each thread processes 4 consecutive groups (float4 per stream):
// groups = 2^23, threads = 2^21.
__global__ __launch_bounds__(256)
void gate2q_kernel(const float* __restrict__ qs_r,
                   const float* __restrict__ qs_i,
                   const float* __restrict__ m_r,
                   const float* __restrict__ m_i,
                   float* __restrict__ out_r,
                   float* __restrict__ out_i)
{
    // Gate matrix into registers (uniform broadcast loads, L1-hit after first wave).
    float Mr[16], Mi[16];
#pragma unroll
    for (int k = 0; k < 16; ++k) { Mr[k] = m_r[k]; Mi[k] = m_i[k]; }

    unsigned t = blockIdx.x * blockDim.x + threadIdx.x;   // [0, 2^21)
    unsigned g = t << 2;                                  // group index, 4-aligned
    // Insert zero bit at position 14, then at position 21 -> base has bits 14,21 clear.
    unsigned y    = ((g >> 14) << 15) | (g & 0x3FFFu);
    unsigned base = ((y >> 21) << 22) | (y & 0x1FFFFFu);

    // Load the 4 paired streams, real+imag, 16B each (coalesced, aligned:
    // low 14 bits of base come straight from g which is 4-aligned).
    float4 xr[4], xi[4];
#pragma unroll
    for (int ap = 0; ap < 2; ++ap) {
#pragma unroll
        for (int bp = 0; bp < 2; ++bp) {
            unsigned off = base + ap * S_A + bp * S_B;
            xr[ap * 2 + bp] = *reinterpret_cast<const float4*>(qs_r + off);
            xi[ap * 2 + bp] = *reinterpret_cast<const float4*>(qs_i + off);
        }
    }

#pragma unroll
    for (int a = 0; a < 2; ++a) {
#pragma unroll
        for (int b = 0; b < 2; ++b) {
            float4 oR = make_float4(0.f, 0.f, 0.f, 0.f);
            float4 oI = make_float4(0.f, 0.f, 0.f, 0.f);
#pragma unroll
            for (int ap = 0; ap < 2; ++ap) {
#pragma unroll
                for (int bp = 0; bp < 2; ++bp) {
                    int   mi = a * 8 + b * 4 + ap * 2 + bp;
                    float mr = Mr[mi];
                    float mm = Mi[mi];
                    const float4& r = xr[ap * 2 + bp];
                    const float4& q = xi[ap * 2 + bp];
                    oR.x += mr * r.x - mm * q.x;
                    oR.y += mr * r.y - mm * q.y;
                    oR.z += mr * r.z - mm * q.z;
                    oR.w += mr * r.w - mm * q.w;
                    oI.x += mr * q.x + mm * r.x;
                    oI.y += mr * q.y + mm * r.y;
                    oI.z += mr * q.z + mm * r.z;
                    oI.w += mr * q.w + mm * r.w;
                }
            }
            unsigned off = base + a * S_A + b * S_B;
            *reinterpret_cast<float4*>(out_r + off) = oR;
            *reinterpret_cast<float4*>(out_i + off) = oI;
        }
    }
}

extern "C" void kernel_launch(void* const* d_in, const int* in_sizes, int n_in,
                              void* d_out, int out_size, void* d_ws, size_t ws_size,
                              hipStream_t stream) {
    const float* qs_r = (const float*)d_in[0];
    const float* qs_i = (const float*)d_in[1];
    const float* m_r  = (const float*)d_in[2];
    const float* m_i  = (const float*)d_in[3];

    float* out_r = (float*)d_out;            // out_real: 2^25 floats
    float* out_i = out_r + N_STATE;          // out_imag: 2^25 floats

    const unsigned n_threads = N_STATE / 4 / 4;  // 2^21: 4 groups of 4 amps per thread
    const unsigned block = 256;
    const unsigned grid  = n_threads / block;    // 8192 blocks

    gate2q_kernel<<<grid, block, 0, stream>>>(qs_r, qs_i, m_r, m_i, out_r, out_i);
}

// Round 3
// 94.199 us; speedup vs baseline: 1.0771x; 1.0771x over previous
//
#include <hip/hip_runtime.h>

// 25 qubits, DIM=2, targets (10, 3) on a row-major (2,)*25 array.
// Axis t has element stride 2^(24-t):
//   axis 10 -> stride 2^14 (gate index 'a')
//   axis 3  -> stride 2^21 (gate index 'b')
// Gate op[a, b, a', b'] flat index = a*8 + b*4 + a'*2 + b'.
// out[base + a*2^14 + b*2^21] = sum_{a',b'} M[a,b,a',b'] * in[base + a'*2^14 + b'*2^21]
// Complex split: outR = Mr*xr - Mi*xi ; outI = Mr*xi + Mi*xr.
//
// R2 -> R3: nontemporal builtins need clang ext_vector_type, not HIP float4.

#define N_STATE  (1u << 25)
#define S_A      (1u << 14)   // stride of target axis 10
#define S_B      (1u << 21)   // stride of target axis 3

typedef float v4f __attribute__((ext_vector_type(4)));

__global__ __launch_bounds__(256)
void gate2q_kernel(const float* __restrict__ qs_r,
                   const float* __restrict__ qs_i,
                   const float* __restrict__ m_r,
                   const float* __restrict__ m_i,
                   float* __restrict__ out_r,
                   float* __restrict__ out_i)
{
    // Gate matrix into registers (uniform address -> scalar loads, L2-hit).
    float Mr[16], Mi[16];
#pragma unroll
    for (int k = 0; k < 16; ++k) { Mr[k] = m_r[k]; Mi[k] = m_i[k]; }

    unsigned t = blockIdx.x * blockDim.x + threadIdx.x;   // [0, 2^21)
    unsigned g = t << 2;                                  // group index, 4-aligned
    // Insert zero bit at position 14, then at position 21 -> base has bits 14,21 clear.
    unsigned y    = ((g >> 14) << 15) | (g & 0x3FFFu);
    unsigned base = ((y >> 21) << 22) | (y & 0x1FFFFFu);

    // Load the 4 paired streams, real+imag, 16B each, nontemporal.
    v4f xr[4], xi[4];
#pragma unroll
    for (int ap = 0; ap < 2; ++ap) {
#pragma unroll
        for (int bp = 0; bp < 2; ++bp) {
            unsigned off = base + ap * S_A + bp * S_B;
            xr[ap * 2 + bp] = __builtin_nontemporal_load(
                reinterpret_cast<const v4f*>(qs_r + off));
            xi[ap * 2 + bp] = __builtin_nontemporal_load(
                reinterpret_cast<const v4f*>(qs_i + off));
        }
    }

#pragma unroll
    for (int a = 0; a < 2; ++a) {
#pragma unroll
        for (int b = 0; b < 2; ++b) {
            v4f oR = (v4f)(0.f);
            v4f oI = (v4f)(0.f);
#pragma unroll
            for (int ap = 0; ap < 2; ++ap) {
#pragma unroll
                for (int bp = 0; bp < 2; ++bp) {
                    int   mi = a * 8 + b * 4 + ap * 2 + bp;
                    float mr = Mr[mi];
                    float mm = Mi[mi];
                    v4f r = xr[ap * 2 + bp];
                    v4f q = xi[ap * 2 + bp];
                    oR += mr * r - mm * q;
                    oI += mr * q + mm * r;
                }
            }
            unsigned off = base + a * S_A + b * S_B;
            __builtin_nontemporal_store(oR, reinterpret_cast<v4f*>(out_r + off));
            __builtin_nontemporal_store(oI, reinterpret_cast<v4f*>(out_i + off));
        }
    }
}

extern "C" void kernel_launch(void* const* d_in, const int* in_sizes, int n_in,
                              void* d_out, int out_size, void* d_ws, size_t ws_size,
                              hipStream_t stream) {
    const float* qs_r = (const float*)d_in[0];
    const float* qs_i = (const float*)d_in[1];
    const float* m_r  = (const float*)d_in[2];
    const float* m_i  = (const float*)d_in[3];

    float* out_r = (float*)d_out;            // out_real: 2^25 floats
    float* out_i = out_r + N_STATE;          // out_imag: 2^25 floats

    const unsigned n_threads = N_STATE / 4 / 4;  // 2^21: 4 groups of 4 amps per thread
    const unsigned block = 256;
    const unsigned grid  = n_threads / block;    // 8192 blocks

    gate2q_kernel<<<grid, block, 0, stream>>>(qs_r, qs_i, m_r, m_i, out_r, out_i);
}